// Round 5
// baseline (195.432 us; speedup 1.0000x reference)
//
#include <hip/hip_runtime.h>

constexpr int Bn = 64, Sn = 512, Hn = 768, Tn = 9;
constexpr int EMS = 12;                  // padded emission row stride (floats)
constexpr int CHUNKS = 32, CLEN = 16;    // CHUNKS*CLEN == Sn
constexpr int WPAD = 776;                // padded Wt row stride (768+8): conflict-free b128

__device__ __forceinline__ float lse9(const float* e) {
    float m01 = fmaxf(e[0], e[1]), m23 = fmaxf(e[2], e[3]);
    float m45 = fmaxf(e[4], e[5]), m67 = fmaxf(e[6], e[7]);
    float m = fmaxf(fmaxf(fmaxf(m01, m23), fmaxf(m45, m67)), e[8]);
    float s = 0.f;
#pragma unroll
    for (int k = 0; k < 9; ++k) s += __expf(e[k] - m);
    return m + __logf(s);
}

// ---------------- K1: emissions = hidden @ W + b (streaming, BW-bound) -------
// 256 thr = 4 waves; wave-per-row; W register-cached (float4 wq[27]) from a
// transposed padded LDS copy (one-time, conflict-free ds_read_b128).
__global__ __launch_bounds__(256, 1) void emis_kernel(
        const float* __restrict__ hidden, const float* __restrict__ W,
        const float* __restrict__ bias, float* __restrict__ em) {
    __shared__ float Wt[Tn * WPAD];       // 27936 B
    const int tid = threadIdx.x;
    const int lane = tid & 63;

    // stage W transposed: Wt[t][h] = W[h*9+t]
    for (int f = tid; f < Hn * Tn; f += 256) {
        int h = f / 9, t = f - 9 * h;
        Wt[t * WPAD + h] = W[f];
    }
    const float myb = (lane < 9) ? bias[lane] : 0.f;
    __syncthreads();

    // per-lane W cache: wq[t*3+k] = W[4*lane+256k + 0..3][t]
    float4 wq[27];
#pragma unroll
    for (int t = 0; t < 9; ++t)
#pragma unroll
        for (int k = 0; k < 3; ++k)
            wq[t * 3 + k] = *reinterpret_cast<const float4*>(
                &Wt[t * WPAD + 4 * lane + 256 * k]);

    const int wid = blockIdx.x * 4 + (tid >> 6);   // 4096 waves
    const int nw  = gridDim.x * 4;
    const int nrows = Bn * Sn;

    int row = wid;
    const float4* hp = reinterpret_cast<const float4*>(hidden + (size_t)row * Hn);
    float4 p0 = hp[lane], p1 = hp[lane + 64], p2 = hp[lane + 128];

    for (; row < nrows; ) {
        const int nxt = row + nw;
        float4 c0 = p0, c1 = p1, c2 = p2;
        if (nxt < nrows) {
            const float4* hq = reinterpret_cast<const float4*>(hidden + (size_t)nxt * Hn);
            p0 = hq[lane]; p1 = hq[lane + 64]; p2 = hq[lane + 128];
        }
        const float hv[12] = {c0.x, c0.y, c0.z, c0.w, c1.x, c1.y, c1.z, c1.w,
                              c2.x, c2.y, c2.z, c2.w};
        float acc[9];
#pragma unroll
        for (int t = 0; t < 9; ++t) acc[t] = 0.f;
#pragma unroll
        for (int k = 0; k < 3; ++k)
#pragma unroll
            for (int c = 0; c < 4; ++c)
#pragma unroll
                for (int t = 0; t < 9; ++t)
                    acc[t] = fmaf(hv[4 * k + c], ((const float*)&wq[t * 3 + k])[c], acc[t]);
        // allreduce butterfly: every lane ends with all 9 sums
#pragma unroll
        for (int m = 1; m < 64; m <<= 1)
#pragma unroll
            for (int t = 0; t < 9; ++t) acc[t] += __shfl_xor(acc[t], m, 64);
        // lane t (<9) selects acc[t] with compile-time indexing
        float v = acc[0];
#pragma unroll
        for (int t = 1; t < 9; ++t) v = (lane == t) ? acc[t] : v;
        if (lane < 9) em[(size_t)row * EMS + lane] = v + myb;
        row = nxt;
    }
}

// ---------------- K2: per-(batch,chunk) 9x9 log-matrix ----------------
__global__ __launch_bounds__(128) void chunk_kernel(
        const float* __restrict__ em, const float* __restrict__ trans,
        const int* __restrict__ labels, float* __restrict__ Mws) {
    const int b = blockIdx.x / CHUNKS;
    const int c = blockIdx.x % CHUNKS;
    const int tid = threadIdx.x;
    const bool act = tid < 81;
    const int i = tid / 9, j = tid % 9;
    __shared__ float Mbuf[2][9][12];
    __shared__ float emch[CLEN][EMS];
    __shared__ int   labch[CLEN];
    const int s0 = c * CLEN;
    const float* emb = em + ((size_t)b * Sn + s0) * EMS;
    for (int idx = tid; idx < CLEN * EMS; idx += 128)
        (&emch[0][0])[idx] = emb[idx];
    if (tid < CLEN) labch[tid] = labels[b * Sn + s0 + tid];
    float tc[9], row[9];
    float nv = (i == j) ? 0.f : -1e30f;
    if (act) {
#pragma unroll
        for (int k = 0; k < 9; ++k) tc[k] = trans[k * 9 + j];
#pragma unroll
        for (int k = 0; k < 9; ++k) row[k] = (k == i) ? 0.f : -1e30f;
    }
    __syncthreads();
    const int sbeg = (c == 0) ? 1 : 0;
    for (int sl = sbeg; sl < CLEN; ++sl) {
        if (act) {
            float e[9];
#pragma unroll
            for (int k = 0; k < 9; ++k) e[k] = row[k] + tc[k];
            float cand = lse9(e) + emch[sl][j];
            if (labch[sl] > -1) nv = cand;
            Mbuf[sl & 1][i][j] = nv;
        }
        __syncthreads();
        if (act) {
#pragma unroll
            for (int k = 0; k < 9; ++k) row[k] = Mbuf[sl & 1][i][k];
        }
    }
    if (act) Mws[(size_t)(b * CHUNKS + c) * 81 + tid] = nv;
}

// ---------------- K3: fold chunks + numerator + output ----------------
__global__ __launch_bounds__(128) void final_kernel(
        const float* __restrict__ em, const float* __restrict__ Mws,
        const float* __restrict__ start, const float* __restrict__ endt,
        const float* __restrict__ trans, const int* __restrict__ labels,
        float* __restrict__ out) {
    const int b = blockIdx.x, tid = threadIdx.x;
    __shared__ float Ml[CHUNKS][9][12];
    __shared__ float red[128];
    for (int idx = tid; idx < CHUNKS * 81; idx += 128) {
        int c = idx / 81, r = idx % 81;
        Ml[c][r / 9][r % 9] = Mws[(size_t)(b * CHUNKS + c) * 81 + r];
    }
    const int* lb = labels + b * Sn;
    float np = 0.f;
    for (int s = tid; s < Sn; s += 128) {
        if (s >= 1) {
            int l = lb[s];
            if (l > -1) {
                int tp = lb[s - 1]; tp = tp > -1 ? tp : 0;
                np += trans[tp * 9 + l] + em[((size_t)b * Sn + s) * EMS + l];
            }
        }
    }
    red[tid] = np;
    __syncthreads();
    for (int off = 64; off > 0; off >>= 1) {
        if (tid < off) red[tid] += red[tid + off];
        __syncthreads();
    }
    if (tid < 9) {
        const int j = tid;
        float alpha[9];
#pragma unroll
        for (int k = 0; k < 9; ++k)
            alpha[k] = start[k] + em[(size_t)b * Sn * EMS + k];
        for (int c = 0; c < CHUNKS; ++c) {
            float e[9];
#pragma unroll
            for (int k = 0; k < 9; ++k) e[k] = alpha[k] + Ml[c][k][j];
            float nv = lse9(e);
#pragma unroll
            for (int k = 0; k < 9; ++k) alpha[k] = __shfl(nv, k, 64);
        }
        if (j == 0) {
            float e[9];
#pragma unroll
            for (int k = 0; k < 9; ++k) e[k] = alpha[k] + endt[k];
            float den = lse9(e);
            int t0 = lb[0] > -1 ? lb[0] : 0;
            float num = red[0] + start[t0] + em[(size_t)b * Sn * EMS + t0];
            int lt = lb[Sn - 1] > -1 ? lb[Sn - 1] : 0;
            num += endt[lt];
            atomicAdd(out, (den - num) * (1.0f / Bn));
        }
    }
}

extern "C" void kernel_launch(void* const* d_in, const int* in_sizes, int n_in,
                              void* d_out, int out_size, void* d_ws, size_t ws_size,
                              hipStream_t stream) {
    const float* hidden = (const float*)d_in[0];
    const float* W      = (const float*)d_in[1];
    const float* bias   = (const float*)d_in[2];
    const float* start  = (const float*)d_in[3];
    const float* endt   = (const float*)d_in[4];
    const float* trans  = (const float*)d_in[5];
    const int*   labels = (const int*)d_in[6];
    float* out = (float*)d_out;

    float* em  = (float*)d_ws;                       // 32768*12 f32 = 1.5 MB
    float* Mws = em + (size_t)Bn * Sn * EMS;         // 64*32*81 f32

    hipMemsetAsync(d_out, 0, sizeof(float), stream);
    emis_kernel<<<1024, 256, 0, stream>>>(hidden, W, bias, em);
    chunk_kernel<<<Bn * CHUNKS, 128, 0, stream>>>(em, trans, labels, Mws);
    final_kernel<<<Bn, 128, 0, stream>>>(em, Mws, start, endt, trans, labels, out);
}